// Round 9
// baseline (316.476 us; speedup 1.0000x reference)
//
#include <hip/hip_runtime.h>

// InstanceRouteOptimizationArea — RUDY map via impulse/cumsum trick.
// Round 9: bucketed work-list splat.
// R8 decode: accum ~35us invariant; R7 PMC: VALUBusy 10%, 830GB/s, occ 35%
// -> cause = 8x record re-read (replication) + window straggler imbalance.
// K1 bbox computes per-net records and wave-aggregated-appends them into
// per-window buckets (records carry row-pair weights + x-quad + dh/dv).
// K2 reads only its bucket slice (contiguous, once), splats into LDS tile,
// x-cumsums, stores. K3/K4/K5 = R8's coalesced tail.

#define NB 256
#define NW 32          // rows per window
#define NWIN 8         // NB/NW
#define NCHUNK 32      // K2 grid = NWIN*NCHUNK = 256
#define K2_THREADS 512

__device__ __forceinline__ long long load_idx(const void* p, long long i, int is64) {
    if (is64) return ((const long long*)p)[i];
    return (long long)((const int*)p)[i];
}

// Record: 32B = 8 floats
//  [0] row (u32 as float bits)   [1] w0   [2] w1   [3] i0|i1<<16 (u32 bits)
//  [4] h0  [5] h1  [6] dh  [7] dv
// Splat: rows {row:w0, row+1:w1} x cols {i0:B(1-h0), i0+1:B h0, i1:-B(1-h1), i1+1:-B h1}

// ---------------- K1: bbox + record append ----------------
__global__ __launch_bounds__(256) void bbox_append(
        const float* __restrict__ pin_pos,
        const float* __restrict__ net_weights,
        const void* __restrict__ netpin_start,
        const void* __restrict__ flat_netpin,
        unsigned* __restrict__ ctr,       // [NWIN], zeroed per launch
        float* __restrict__ buf,          // [NWIN][cap][8]
        int num_nets, int num_pins, int cap) {
    const int n = blockIdx.x * blockDim.x + threadIdx.x;
    const int lane = threadIdx.x & 63;
    const int is64 = (((const int*)netpin_start)[1] == 0);
    const float BSX  = 3.90625f;
    const float INVB = 1.0f / 3.90625f;

    int   tgt[4] = { -1, -1, -1, -1 };   // target window per append slot
    float recA[8], recB[8];

    if (n < num_nets) {
        long long s = load_idx(netpin_start, n, is64);
        long long e = load_idx(netpin_start, n + 1, is64);
        if (e > s) {
            float xmn = 3e38f, xmx = -3e38f, ymn = 3e38f, ymx = -3e38f;
            for (long long q = s; q < e; ++q) {
                long long pin = load_idx(flat_netpin, q, is64);
                float px = pin_pos[pin], py = pin_pos[pin + num_pins];
                xmn = fminf(xmn, px); xmx = fmaxf(xmx, px);
                ymn = fminf(ymn, py); ymx = fmaxf(ymx, py);
            }
            float wx = xmx - xmn, wy = ymx - ymn;
            float area = fmaxf(wx * wy, 1e-6f);
            float w = net_weights[n];
            float dh = w * wx / area;
            float dv = w * wy / area;
            float tx0 = xmn * INVB, g0 = floorf(tx0);
            float tx1 = xmx * INVB, g1 = floorf(tx1);
            int i0 = (int)g0, i1 = (int)g1;
            float h0 = tx0 - g0, h1 = tx1 - g1;
            unsigned ii = (unsigned)(i0 & 0xffff) | ((unsigned)(i1 & 0xffff) << 16);

            float ty0 = ymn * INVB, fj0 = floorf(ty0);
            float ty1 = ymx * INVB, fj1 = floorf(ty1);
            int j0 = (int)fj0, j1 = (int)fj1;
            float f0 = ty0 - fj0, f1 = ty1 - fj1;

            if (j0 <= 255) {             // record A (+)
                recA[0] = __uint_as_float((unsigned)j0);
                recA[1] = BSX * (1.f - f0);
                recA[2] = BSX * f0;
                recA[3] = __uint_as_float(ii);
                recA[4] = h0; recA[5] = h1; recA[6] = dh; recA[7] = dv;
                tgt[0] = j0 >> 5;
                int w2 = (j0 + 1) >> 5;
                if (j0 + 1 <= 255 && w2 != tgt[0]) tgt[1] = w2;
            }
            if (j1 <= 255) {             // record B (-)
                recB[0] = __uint_as_float((unsigned)j1);
                recB[1] = -BSX * (1.f - f1);
                recB[2] = -BSX * f1;
                recB[3] = __uint_as_float(ii);
                recB[4] = h0; recB[5] = h1; recB[6] = dh; recB[7] = dv;
                tgt[2] = j1 >> 5;
                int w2 = (j1 + 1) >> 5;
                if (j1 + 1 <= 255 && w2 != tgt[2]) tgt[3] = w2;
            }
        }
    }

    // Wave-aggregated append: 4 slots x 8 windows of ballot rounds.
    for (int r = 0; r < 4; ++r) {
        int tw = tgt[r];
        const float* rec = (r < 2) ? recA : recB;
        for (int w = 0; w < NWIN; ++w) {
            unsigned long long m = __ballot(tw == w);
            if (m == 0ull) continue;
            int leader = __ffsll((long long)m) - 1;
            unsigned base = 0;
            if (lane == leader)
                base = atomicAdd(&ctr[w], (unsigned)__popcll(m));
            base = __shfl(base, leader);
            if (tw == w) {
                unsigned idx = base + (unsigned)__popcll(m & ((1ull << lane) - 1ull));
                if (idx < (unsigned)cap) {
                    float4* dst = (float4*)(buf + (((size_t)w * cap) + idx) * 8);
                    dst[0] = make_float4(rec[0], rec[1], rec[2], rec[3]);
                    dst[1] = make_float4(rec[4], rec[5], rec[6], rec[7]);
                }
            }
        }
    }
}

// ---------------- K2: bucket splat + x-cumsum + store ----------------
__global__ __launch_bounds__(K2_THREADS) void accum3(
        const unsigned* __restrict__ ctr,
        const float* __restrict__ buf,
        float* __restrict__ P,          // [NCHUNK][2][NB][NB]
        int cap) {
    __shared__ float acc[2 * NW * NB];  // 64 KiB
    const int win   = blockIdx.x & (NWIN - 1);
    const int chunk = blockIdx.x >> 3;      // NWIN == 8
    const int r0    = win * NW;
    const int tid   = threadIdx.x;
    const float BSX = 3.90625f;

    for (int i = tid; i < 2 * NW * NB; i += K2_THREADS) acc[i] = 0.f;
    __syncthreads();

    int cw = (int)ctr[win];
    if (cw > cap) cw = cap;
    const int a0 = (int)((long long)cw * chunk / NCHUNK);
    const int a1 = (int)((long long)cw * (chunk + 1) / NCHUNK);
    const float4* rb = (const float4*)(buf + (size_t)win * cap * 8);

    for (int i = a0 + tid; i < a1; i += K2_THREADS) {
        float4 ra = rb[2 * i];
        float4 r2 = rb[2 * i + 1];
        int row = (int)__float_as_uint(ra.x);
        float w0 = ra.y, w1 = ra.z;
        unsigned ii = __float_as_uint(ra.w);
        int i0 = (int)(ii & 0xffffu), i1 = (int)(ii >> 16);
        float h0 = r2.x, h1 = r2.y, dh = r2.z, dv = r2.w;
        int   xx[4] = { i0, i0 + 1, i1, i1 + 1 };
        float ax[4] = { BSX * (1.f - h0), BSX * h0, -BSX * (1.f - h1), -BSX * h1 };
        #pragma unroll
        for (int rr = 0; rr < 2; ++rr) {
            int ro = row + rr - r0;
            float rw = rr ? w1 : w0;
            if ((unsigned)ro >= NW || rw == 0.f) continue;
            float* bh = acc + ro * NB;
            float* bv = acc + NW * NB + ro * NB;
            float wh = rw * dh, wv = rw * dv;
            #pragma unroll
            for (int p = 0; p < 4; ++p) {
                int x = xx[p];
                if (x >= NB) continue;
                atomicAdd(bh + x, ax[p] * wh);
                atomicAdd(bv + x, ax[p] * wv);
            }
        }
    }
    __syncthreads();

    // In-tile x-cumsum: one wave per row, shfl segmented scan.
    const int wave = tid >> 6, lane = tid & 63;
    for (int row = wave; row < 2 * NW; row += (K2_THREADS / 64)) {
        float* base = acc + row * NB;
        float carry = 0.f;
        #pragma unroll
        for (int seg = 0; seg < NB / 64; ++seg) {
            float v = base[seg * 64 + lane];
            #pragma unroll
            for (int off = 1; off < 64; off <<= 1) {
                float u = __shfl_up(v, off);
                if (lane >= off) v += u;
            }
            v += carry;
            base[seg * 64 + lane] = v;
            carry = __shfl(v, 63);
        }
    }
    __syncthreads();

    // Coalesced float4 store: P[chunk][plane][r0+row][x]
    const float4* a4 = (const float4*)acc;
    float4* P4 = (float4*)P;
    for (int i = tid; i < 2 * NW * (NB / 4); i += K2_THREADS) {
        int p   = i / (NW * 64);
        int rem = i - p * (NW * 64);
        int row = rem / 64;
        int x4  = rem - row * 64;
        P4[(((long long)chunk * 2 + p) * NB + (r0 + row)) * 64 + x4] = a4[i];
    }
}

// ---------------- K3: chunk-sum (coalesced) + transpose ----------------
__global__ __launch_bounds__(256) void chunk_reduce_T(
        const float* __restrict__ P, float* __restrict__ GT) {
    const int p = blockIdx.x >> 8;
    const int y = blockIdx.x & 255;
    const int x = threadIdx.x;
    float s = 0.f;
    #pragma unroll 8
    for (int c = 0; c < NCHUNK; ++c)
        s += P[(((long long)c * 2 + p) * NB + y) * NB + x];
    GT[((long long)p * NB + x) * NB + y] = s;
}

// ---------------- K4: y-cumsum + util (coalesced) ----------------
__global__ __launch_bounds__(512) void yscan_util(
        const float* __restrict__ GT, float* __restrict__ utilT) {
    __shared__ float sbuf[2 * NB];
    const int x = blockIdx.x;
    const int plane = threadIdx.x >> 8;
    const int y = threadIdx.x & (NB - 1);
    float* b = sbuf + plane * NB;
    b[y] = GT[((long long)plane * NB + x) * NB + y];
    #pragma unroll
    for (int off = 1; off < NB; off <<= 1) {
        __syncthreads();
        float a = (y >= off) ? b[y - off] : 0.0f;
        __syncthreads();
        b[y] += a;
    }
    __syncthreads();
    if (plane == 0) {
        const float INV_CH = 1.0f / (3.90625f * 3.90625f * 1.5625f);
        const float INV_CV = 1.0f / (3.90625f * 3.90625f * 1.45f);
        float u = fmaxf(sbuf[y] * INV_CH, sbuf[NB + y] * INV_CV);
        u = fminf(fmaxf(u, 0.5f), 2.0f);
        utilT[x * NB + y] = u;
    }
}

// ---------------- K5: per-instance area (util transposed [x][y]) --------
__global__ void instance_area(const float* __restrict__ pos,
                              const float* __restrict__ nsx,
                              const float* __restrict__ nsy,
                              const float* __restrict__ utilT,
                              float* __restrict__ out,
                              int num_movable, int num_nodes) {
    int i = blockIdx.x * blockDim.x + threadIdx.x;
    if (i >= num_movable) return;
    const float BSX = 3.90625f;
    const float INVB = 1.0f / 3.90625f;
    float x0f = pos[i];
    float y0f = pos[num_nodes + i];
    float x1f = x0f + nsx[i];
    float y1f = y0f + nsy[i];
    int kx0 = max(0, min(NB - 1, (int)floorf(x0f * INVB)));
    int kx1 = max(0, min(NB - 1, (int)floorf(x1f * INVB)));
    int ky0 = max(0, min(NB - 1, (int)floorf(y0f * INVB)));
    int ky1 = max(0, min(NB - 1, (int)floorf(y1f * INVB)));
    float acc = 0.0f;
    for (int kx = kx0; kx <= kx1; ++kx) {
        float bx = kx * BSX;
        float ovx = fmaxf(fminf(x1f, bx + BSX) - fmaxf(x0f, bx), 0.0f);
        const float* ucol = utilT + kx * NB;
        float accy = 0.0f;
        for (int ky = ky0; ky <= ky1; ++ky) {
            float by = ky * BSX;
            float ovy = fmaxf(fminf(y1f, by + BSX) - fmaxf(y0f, by), 0.0f);
            accy += ovy * ucol[ky];
        }
        acc += accy * ovx;
    }
    out[i] = acc;
}

// ---------------- fallback (tiny workspace): round-1 style ----------------
__global__ void fb_zero(float* g, int n) {
    int i = blockIdx.x * blockDim.x + threadIdx.x;
    int stride = gridDim.x * blockDim.x;
    for (; i < n; i += stride) g[i] = 0.0f;
}

__global__ void fb_scatter(const float* __restrict__ pin_pos,
                           const float* __restrict__ net_weights,
                           const void* __restrict__ netpin_start,
                           const void* __restrict__ flat_netpin,
                           float* __restrict__ G2,
                           int num_nets, int num_pins) {
    int n = blockIdx.x * blockDim.x + threadIdx.x;
    if (n >= num_nets) return;
    const int is64 = (((const int*)netpin_start)[1] == 0);
    long long s = load_idx(netpin_start, n, is64);
    long long e = load_idx(netpin_start, n + 1, is64);
    if (e <= s) return;
    float xmn = 3e38f, xmx = -3e38f, ymn = 3e38f, ymx = -3e38f;
    for (long long p = s; p < e; ++p) {
        long long pin = load_idx(flat_netpin, p, is64);
        float px = pin_pos[pin], py = pin_pos[pin + num_pins];
        xmn = fminf(xmn, px); xmx = fmaxf(xmx, px);
        ymn = fminf(ymn, py); ymx = fmaxf(ymx, py);
    }
    float wx = xmx - xmn, wy = ymx - ymn;
    float area = fmaxf(wx * wy, 1e-6f);
    float w = net_weights[n];
    float dh = w * wx / area, dv = w * wy / area;
    const float BSX = 3.90625f, INVB = 1.0f / 3.90625f;
    int jx[4]; float ax[4]; int jy[4]; float ay[4];
    float t, fj, f; int j;
    t = xmn * INVB; fj = floorf(t); j = (int)fj; f = t - fj;
    jx[0] = j; ax[0] = BSX * (1.f - f); jx[1] = j + 1; ax[1] = BSX * f;
    t = xmx * INVB; fj = floorf(t); j = (int)fj; f = t - fj;
    jx[2] = j; ax[2] = -BSX * (1.f - f); jx[3] = j + 1; ax[3] = -BSX * f;
    t = ymn * INVB; fj = floorf(t); j = (int)fj; f = t - fj;
    jy[0] = j; ay[0] = BSX * (1.f - f); jy[1] = j + 1; ay[1] = BSX * f;
    t = ymx * INVB; fj = floorf(t); j = (int)fj; f = t - fj;
    jy[2] = j; ay[2] = -BSX * (1.f - f); jy[3] = j + 1; ay[3] = -BSX * f;
    #pragma unroll
    for (int b = 0; b < 4; ++b) {
        int y = jy[b];
        if (y < 0 || y >= NB) continue;
        #pragma unroll
        for (int a2 = 0; a2 < 4; ++a2) {
            int x = jx[a2];
            if (x < 0 || x >= NB) continue;
            float g = ax[a2] * ay[b];
            atomicAdd(&G2[(y * NB + x) * 2],     dh * g);
            atomicAdd(&G2[(y * NB + x) * 2 + 1], dv * g);
        }
    }
}

__global__ void fb_rowscan(float2* G2) {
    int y = blockIdx.x, t = threadIdx.x;
    __shared__ float sh[NB]; __shared__ float sv[NB];
    float2 v = G2[y * NB + t];
    sh[t] = v.x; sv[t] = v.y;
    #pragma unroll
    for (int off = 1; off < NB; off <<= 1) {
        __syncthreads();
        float a = (t >= off) ? sh[t - off] : 0.0f;
        float b = (t >= off) ? sv[t - off] : 0.0f;
        __syncthreads();
        sh[t] += a; sv[t] += b;
    }
    __syncthreads();
    G2[y * NB + t] = make_float2(sh[t], sv[t]);
}

__global__ void fb_colscan(const float2* __restrict__ G2, float* __restrict__ utilT) {
    int x = blockIdx.x, t = threadIdx.x;
    const float INV_CH = 1.0f / (3.90625f * 3.90625f * 1.5625f);
    const float INV_CV = 1.0f / (3.90625f * 3.90625f * 1.45f);
    __shared__ float sh[NB]; __shared__ float sv[NB];
    float2 g = G2[t * NB + x];
    sh[t] = g.x; sv[t] = g.y;
    #pragma unroll
    for (int off = 1; off < NB; off <<= 1) {
        __syncthreads();
        float a = (t >= off) ? sh[t - off] : 0.0f;
        float b = (t >= off) ? sv[t - off] : 0.0f;
        __syncthreads();
        sh[t] += a; sv[t] += b;
    }
    __syncthreads();
    float u = fmaxf(sh[t] * INV_CH, sv[t] * INV_CV);
    utilT[x * NB + t] = fminf(fmaxf(u, 0.5f), 2.0f);
}

extern "C" void kernel_launch(void* const* d_in, const int* in_sizes, int n_in,
                              void* d_out, int out_size, void* d_ws, size_t ws_size,
                              hipStream_t stream) {
    const float* pos          = (const float*)d_in[0];
    const float* pin_pos      = (const float*)d_in[1];
    const float* nsx          = (const float*)d_in[2];
    const float* nsy          = (const float*)d_in[3];
    const float* net_weights  = (const float*)d_in[4];
    const void*  netpin_start = d_in[5];
    const void*  flat_netpin  = d_in[6];
    float* out = (float*)d_out;

    int num_pins    = in_sizes[1] / 2;
    int num_nodes   = in_sizes[2];
    int num_nets    = in_sizes[4];
    int num_movable = out_size;

    // cap: worst case both records + crosses land in one window
    int cap = 2 * num_nets + num_nets / 4 + 64;

    // ws (floats): ctr[16] | buf[NWIN*cap*8] | P[32*2*65536] | GT[2*65536] | ut[65536]
    size_t ctr_off = 0;
    size_t buf_off = 16;
    size_t buf_f   = (size_t)NWIN * cap * 8;
    size_t P_off   = buf_off + buf_f;
    size_t P_f     = (size_t)NCHUNK * 2 * NB * NB;
    size_t GT_off  = P_off + P_f;
    size_t ut_off  = GT_off + 2LL * NB * NB;
    size_t need    = (ut_off + (size_t)NB * NB) * sizeof(float);

    if (ws_size >= need) {
        float* base = (float*)d_ws;
        unsigned* ctr = (unsigned*)(base + ctr_off);
        float*    buf = base + buf_off;
        float*    P   = base + P_off;
        float*    GT  = base + GT_off;
        float*    ut  = base + ut_off;

        hipMemsetAsync(ctr, 0, 16 * sizeof(unsigned), stream);
        int g1 = (num_nets + 255) / 256;
        bbox_append<<<g1, 256, 0, stream>>>(pin_pos, net_weights, netpin_start,
                                            flat_netpin, ctr, buf,
                                            num_nets, num_pins, cap);
        accum3<<<NWIN * NCHUNK, K2_THREADS, 0, stream>>>(ctr, buf, P, cap);
        chunk_reduce_T<<<2 * NB, 256, 0, stream>>>(P, GT);
        yscan_util<<<NB, 512, 0, stream>>>(GT, ut);
        int gi = (num_movable + 255) / 256;
        instance_area<<<gi, 256, 0, stream>>>(pos, nsx, nsy, ut, out,
                                              num_movable, num_nodes);
        return;
    }

    // -------- fallback: round-1 style (768KB workspace) --------
    {
        float* G2   = (float*)d_ws;
        float* util = G2 + NB * NB * 2;    // utilT [x][y]
        fb_zero<<<256, 256, 0, stream>>>(G2, NB * NB * 2);
        int gn = (num_nets + 255) / 256;
        fb_scatter<<<gn, 256, 0, stream>>>(pin_pos, net_weights, netpin_start,
                                           flat_netpin, G2, num_nets, num_pins);
        fb_rowscan<<<NB, 256, 0, stream>>>((float2*)G2);
        fb_colscan<<<NB, 256, 0, stream>>>((const float2*)G2, util);
        int gi = (num_movable + 255) / 256;
        instance_area<<<gi, 256, 0, stream>>>(pos, nsx, nsy, util, out,
                                              num_movable, num_nodes);
    }
}

// Round 10
// 56.318 us; speedup vs baseline: 5.6195x; 5.6195x over previous
//
#include <hip/hip_runtime.h>

// InstanceRouteOptimizationArea — RUDY map via impulse/cumsum trick.
// Round 10: L2-local streaming splat.
// R8 decode: accum ~35us = latency-limited stream (~700GB/s) of cross-XCD
// records + 16MB partials. Fix: NWIN=32 x NCHUNK=8 (16KB LDS, 4 blk/CU),
// chunk = blockIdx&7 so all 32 window-blocks of a chunk share one XCD ->
// record slice L2-resident; merged 32B records, no filter, linear stream;
// P shrunk to 4MB and stored transposed (kills the transpose kernel).
// Pipeline: K1 bbox(records) -> K2 accum(splat+x-cumsum, store P_T) ->
//           K3 yscan_util -> K4 instance_area.

#define NB 256
#define NW 8           // rows per window
#define NWIN 32        // NB/NW
#define NCHUNK 8       // == XCD count; grid K2 = NWIN*NCHUNK = 256
#define K2_THREADS 512

__device__ __forceinline__ long long load_idx(const void* p, long long i, int is64) {
    if (is64) return ((const long long*)p)[i];
    return (long long)((const int*)p)[i];
}

// ---------------- K1: per-net bbox -> merged 32B record ----------------
// rec[n] = float4{ymn,ymx,xmn,xmx}, float4{dh,dv,0,0}
__global__ void bbox_kernel(const float* __restrict__ pin_pos,
                            const float* __restrict__ net_weights,
                            const void* __restrict__ netpin_start,
                            const void* __restrict__ flat_netpin,
                            float4* __restrict__ rec,
                            int num_nets, int num_pins) {
    int gid = blockIdx.x * blockDim.x + threadIdx.x;
    int n = gid >> 2, k = gid & 3;
    if (n >= num_nets) return;
    const int is64 = (((const int*)netpin_start)[1] == 0);
    long long s = load_idx(netpin_start, n, is64);
    long long e = load_idx(netpin_start, n + 1, is64);
    float xmn = 3e38f, xmx = -3e38f, ymn = 3e38f, ymx = -3e38f;
    if (e - s == 4) {
        long long pin = load_idx(flat_netpin, s + k, is64);
        float px = pin_pos[pin], py = pin_pos[pin + num_pins];
        xmn = px; xmx = px; ymn = py; ymx = py;
    } else if (k == 0) {
        for (long long p = s; p < e; ++p) {
            long long pin = load_idx(flat_netpin, p, is64);
            float px = pin_pos[pin], py = pin_pos[pin + num_pins];
            xmn = fminf(xmn, px); xmx = fmaxf(xmx, px);
            ymn = fminf(ymn, py); ymx = fmaxf(ymx, py);
        }
    }
    #pragma unroll
    for (int m = 1; m <= 2; m <<= 1) {
        xmn = fminf(xmn, __shfl_xor(xmn, m));
        xmx = fmaxf(xmx, __shfl_xor(xmx, m));
        ymn = fminf(ymn, __shfl_xor(ymn, m));
        ymx = fmaxf(ymx, __shfl_xor(ymx, m));
    }
    if (k) return;
    if (e <= s) {
        rec[2 * n]     = make_float4(3e9f, 3e9f, 3e9f, 3e9f);  // rows OOR -> skipped
        rec[2 * n + 1] = make_float4(0.f, 0.f, 0.f, 0.f);
        return;
    }
    float wx = xmx - xmn, wy = ymx - ymn;
    float area = fmaxf(wx * wy, 1e-6f);
    float w = net_weights[n];
    rec[2 * n]     = make_float4(ymn, ymx, xmn, xmx);
    rec[2 * n + 1] = make_float4(w * wx / area, w * wy / area, 0.f, 0.f);
}

// ------- K2: linear record stream + LDS splat + x-cumsum + P_T store -------
__global__ __launch_bounds__(K2_THREADS) void accum4(
        const float4* __restrict__ rb,
        float* __restrict__ PT,          // [NCHUNK][2][NB(x)][NB(y)]
        int num_nets) {
    __shared__ float acc[2 * NW * NB];   // 16 KiB: [plane][row][x]
    const int win   = blockIdx.x >> 3;   // 0..31
    const int chunk = blockIdx.x & 7;    // 0..7 -> same-chunk blocks co-XCD
    const int r0    = win * NW;
    const int tid   = threadIdx.x;
    const float BSX  = 3.90625f;
    const float INVB = 1.0f / 3.90625f;

    for (int i = tid; i < 2 * NW * NB; i += K2_THREADS) acc[i] = 0.f;
    __syncthreads();

    const int c0 = (int)((long long)num_nets * chunk / NCHUNK);
    const int c1 = (int)((long long)num_nets * (chunk + 1) / NCHUNK);
    #pragma unroll 2
    for (int n = c0 + tid; n < c1; n += K2_THREADS) {
        float4 a = rb[2 * n];
        float ty0 = a.x * INVB, fj0 = floorf(ty0);
        float ty1 = a.y * INVB, fj1 = floorf(ty1);
        int j0 = (int)fj0, j1 = (int)fj1;
        // any of rows {j0,j0+1,j1,j1+1} in [r0, r0+NW)?
        bool hit = ((unsigned)(j0 + 1 - r0) <= NW) || ((unsigned)(j1 + 1 - r0) <= NW);
        if (!hit) continue;
        float4 b = rb[2 * n + 1];
        float f0 = ty0 - fj0, f1 = ty1 - fj1;
        float tx0 = a.z * INVB, g0 = floorf(tx0);
        float tx1 = a.w * INVB, g1 = floorf(tx1);
        int i0 = (int)g0, i1 = (int)g1;
        float h0 = tx0 - g0, h1 = tx1 - g1;
        int   xx[4] = { i0, i0 + 1, i1, i1 + 1 };
        float ax[4] = { BSX * (1.f - h0), BSX * h0, -BSX * (1.f - h1), -BSX * h1 };
        int   rr[4] = { j0, j0 + 1, j1, j1 + 1 };
        float rw[4] = { BSX * (1.f - f0), BSX * f0, -BSX * (1.f - f1), -BSX * f1 };
        #pragma unroll
        for (int q = 0; q < 4; ++q) {
            int ro = rr[q] - r0;
            if ((unsigned)ro >= NW) continue;
            float wh = rw[q] * b.x;
            float wv = rw[q] * b.y;
            float* bh = acc + ro * NB;
            float* bv = acc + NW * NB + ro * NB;
            #pragma unroll
            for (int p = 0; p < 4; ++p) {
                int x = xx[p];
                if (x >= NB) continue;
                atomicAdd(bh + x, ax[p] * wh);
                atomicAdd(bv + x, ax[p] * wv);
            }
        }
    }
    __syncthreads();

    // x-cumsum: 16 rows (2 planes x 8), one wave per row.
    const int wave = tid >> 6, lane = tid & 63;
    for (int row = wave; row < 2 * NW; row += (K2_THREADS / 64)) {
        float* base = acc + row * NB;
        float carry = 0.f;
        #pragma unroll
        for (int seg = 0; seg < NB / 64; ++seg) {
            float v = base[seg * 64 + lane];
            #pragma unroll
            for (int off = 1; off < 64; off <<= 1) {
                float u = __shfl_up(v, off);
                if (lane >= off) v += u;
            }
            v += carry;
            base[seg * 64 + lane] = v;
            carry = __shfl(v, 63);
        }
    }
    __syncthreads();

    // Transposed store: PT[chunk][plane][x][r0..r0+8) -- 1024 float4 slots.
    for (int i = tid; i < 2 * NB * 2; i += K2_THREADS) {
        int p    = i >> 9;          // plane
        int rem  = i & 511;
        int x    = rem >> 1;
        int half = rem & 1;         // which 4 of the 8 y values
        int base = p * NW * NB;
        float4 v;
        v.x = acc[base + (half * 4 + 0) * NB + x];
        v.y = acc[base + (half * 4 + 1) * NB + x];
        v.z = acc[base + (half * 4 + 2) * NB + x];
        v.w = acc[base + (half * 4 + 3) * NB + x];
        float* dst = PT + ((((long long)chunk * 2 + p) * NB + x) * NB) + r0 + half * 4;
        *(float4*)dst = v;
    }
}

// ---------------- K3: chunk-sum + y-cumsum + util (all coalesced) --------
__global__ __launch_bounds__(512) void yscan_util(
        const float* __restrict__ PT, float* __restrict__ utilT) {
    __shared__ float buf[2 * NB];
    const int x = blockIdx.x;
    const int plane = threadIdx.x >> 8;
    const int y = threadIdx.x & (NB - 1);
    float s = 0.f;
    #pragma unroll
    for (int c = 0; c < NCHUNK; ++c)
        s += PT[(((long long)c * 2 + plane) * NB + x) * NB + y];
    float* b = buf + plane * NB;
    b[y] = s;
    #pragma unroll
    for (int off = 1; off < NB; off <<= 1) {
        __syncthreads();
        float a = (y >= off) ? b[y - off] : 0.0f;
        __syncthreads();
        b[y] += a;
    }
    __syncthreads();
    if (plane == 0) {
        const float INV_CH = 1.0f / (3.90625f * 3.90625f * 1.5625f);
        const float INV_CV = 1.0f / (3.90625f * 3.90625f * 1.45f);
        float u = fmaxf(buf[y] * INV_CH, buf[NB + y] * INV_CV);
        u = fminf(fmaxf(u, 0.5f), 2.0f);
        utilT[x * NB + y] = u;
    }
}

// ---------------- K4: per-instance area (util transposed [x][y]) --------
__global__ void instance_area(const float* __restrict__ pos,
                              const float* __restrict__ nsx,
                              const float* __restrict__ nsy,
                              const float* __restrict__ utilT,
                              float* __restrict__ out,
                              int num_movable, int num_nodes) {
    int i = blockIdx.x * blockDim.x + threadIdx.x;
    if (i >= num_movable) return;
    const float BSX = 3.90625f;
    const float INVB = 1.0f / 3.90625f;
    float x0f = pos[i];
    float y0f = pos[num_nodes + i];
    float x1f = x0f + nsx[i];
    float y1f = y0f + nsy[i];
    int kx0 = max(0, min(NB - 1, (int)floorf(x0f * INVB)));
    int kx1 = max(0, min(NB - 1, (int)floorf(x1f * INVB)));
    int ky0 = max(0, min(NB - 1, (int)floorf(y0f * INVB)));
    int ky1 = max(0, min(NB - 1, (int)floorf(y1f * INVB)));
    float acc = 0.0f;
    for (int kx = kx0; kx <= kx1; ++kx) {
        float bx = kx * BSX;
        float ovx = fmaxf(fminf(x1f, bx + BSX) - fmaxf(x0f, bx), 0.0f);
        const float* ucol = utilT + kx * NB;
        float accy = 0.0f;
        for (int ky = ky0; ky <= ky1; ++ky) {
            float by = ky * BSX;
            float ovy = fmaxf(fminf(y1f, by + BSX) - fmaxf(y0f, by), 0.0f);
            accy += ovy * ucol[ky];
        }
        acc += accy * ovx;
    }
    out[i] = acc;
}

// ---------------- fallback (tiny workspace): round-1 style ----------------
__global__ void fb_zero(float* g, int n) {
    int i = blockIdx.x * blockDim.x + threadIdx.x;
    int stride = gridDim.x * blockDim.x;
    for (; i < n; i += stride) g[i] = 0.0f;
}

__global__ void fb_scatter(const float* __restrict__ pin_pos,
                           const float* __restrict__ net_weights,
                           const void* __restrict__ netpin_start,
                           const void* __restrict__ flat_netpin,
                           float* __restrict__ G2,
                           int num_nets, int num_pins) {
    int n = blockIdx.x * blockDim.x + threadIdx.x;
    if (n >= num_nets) return;
    const int is64 = (((const int*)netpin_start)[1] == 0);
    long long s = load_idx(netpin_start, n, is64);
    long long e = load_idx(netpin_start, n + 1, is64);
    if (e <= s) return;
    float xmn = 3e38f, xmx = -3e38f, ymn = 3e38f, ymx = -3e38f;
    for (long long p = s; p < e; ++p) {
        long long pin = load_idx(flat_netpin, p, is64);
        float px = pin_pos[pin], py = pin_pos[pin + num_pins];
        xmn = fminf(xmn, px); xmx = fmaxf(xmx, px);
        ymn = fminf(ymn, py); ymx = fmaxf(ymx, py);
    }
    float wx = xmx - xmn, wy = ymx - ymn;
    float area = fmaxf(wx * wy, 1e-6f);
    float w = net_weights[n];
    float dh = w * wx / area, dv = w * wy / area;
    const float BSX = 3.90625f, INVB = 1.0f / 3.90625f;
    int jx[4]; float ax[4]; int jy[4]; float ay[4];
    float t, fj, f; int j;
    t = xmn * INVB; fj = floorf(t); j = (int)fj; f = t - fj;
    jx[0] = j; ax[0] = BSX * (1.f - f); jx[1] = j + 1; ax[1] = BSX * f;
    t = xmx * INVB; fj = floorf(t); j = (int)fj; f = t - fj;
    jx[2] = j; ax[2] = -BSX * (1.f - f); jx[3] = j + 1; ax[3] = -BSX * f;
    t = ymn * INVB; fj = floorf(t); j = (int)fj; f = t - fj;
    jy[0] = j; ay[0] = BSX * (1.f - f); jy[1] = j + 1; ay[1] = BSX * f;
    t = ymx * INVB; fj = floorf(t); j = (int)fj; f = t - fj;
    jy[2] = j; ay[2] = -BSX * (1.f - f); jy[3] = j + 1; ay[3] = -BSX * f;
    #pragma unroll
    for (int b = 0; b < 4; ++b) {
        int y = jy[b];
        if (y < 0 || y >= NB) continue;
        #pragma unroll
        for (int a2 = 0; a2 < 4; ++a2) {
            int x = jx[a2];
            if (x < 0 || x >= NB) continue;
            float g = ax[a2] * ay[b];
            atomicAdd(&G2[(y * NB + x) * 2],     dh * g);
            atomicAdd(&G2[(y * NB + x) * 2 + 1], dv * g);
        }
    }
}

__global__ void fb_rowscan(float2* G2) {
    int y = blockIdx.x, t = threadIdx.x;
    __shared__ float sh[NB]; __shared__ float sv[NB];
    float2 v = G2[y * NB + t];
    sh[t] = v.x; sv[t] = v.y;
    #pragma unroll
    for (int off = 1; off < NB; off <<= 1) {
        __syncthreads();
        float a = (t >= off) ? sh[t - off] : 0.0f;
        float b = (t >= off) ? sv[t - off] : 0.0f;
        __syncthreads();
        sh[t] += a; sv[t] += b;
    }
    __syncthreads();
    G2[y * NB + t] = make_float2(sh[t], sv[t]);
}

__global__ void fb_colscan(const float2* __restrict__ G2, float* __restrict__ utilT) {
    int x = blockIdx.x, t = threadIdx.x;
    const float INV_CH = 1.0f / (3.90625f * 3.90625f * 1.5625f);
    const float INV_CV = 1.0f / (3.90625f * 3.90625f * 1.45f);
    __shared__ float sh[NB]; __shared__ float sv[NB];
    float2 g = G2[t * NB + x];
    sh[t] = g.x; sv[t] = g.y;
    #pragma unroll
    for (int off = 1; off < NB; off <<= 1) {
        __syncthreads();
        float a = (t >= off) ? sh[t - off] : 0.0f;
        float b = (t >= off) ? sv[t - off] : 0.0f;
        __syncthreads();
        sh[t] += a; sv[t] += b;
    }
    __syncthreads();
    float u = fmaxf(sh[t] * INV_CH, sv[t] * INV_CV);
    utilT[x * NB + t] = fminf(fmaxf(u, 0.5f), 2.0f);
}

extern "C" void kernel_launch(void* const* d_in, const int* in_sizes, int n_in,
                              void* d_out, int out_size, void* d_ws, size_t ws_size,
                              hipStream_t stream) {
    const float* pos          = (const float*)d_in[0];
    const float* pin_pos      = (const float*)d_in[1];
    const float* nsx          = (const float*)d_in[2];
    const float* nsy          = (const float*)d_in[3];
    const float* net_weights  = (const float*)d_in[4];
    const void*  netpin_start = d_in[5];
    const void*  flat_netpin  = d_in[6];
    float* out = (float*)d_out;

    int num_pins    = in_sizes[1] / 2;
    int num_nodes   = in_sizes[2];
    int num_nets    = in_sizes[4];
    int num_movable = out_size;

    // ws (floats): rec[8n] | PT[8*2*NB*NB] | utilT[NB*NB]
    size_t rec_f = 8LL * num_nets;
    size_t PT_f  = (size_t)NCHUNK * 2 * NB * NB;
    size_t ut_f  = (size_t)NB * NB;
    size_t need  = (rec_f + PT_f + ut_f) * sizeof(float);

    if (ws_size >= need) {
        float* base = (float*)d_ws;
        float4* rec = (float4*)base;
        float*  PT  = base + rec_f;
        float*  ut  = PT + PT_f;

        int g1 = (4 * num_nets + 255) / 256;
        bbox_kernel<<<g1, 256, 0, stream>>>(pin_pos, net_weights, netpin_start,
                                            flat_netpin, rec, num_nets, num_pins);
        accum4<<<NWIN * NCHUNK, K2_THREADS, 0, stream>>>(rec, PT, num_nets);
        yscan_util<<<NB, 512, 0, stream>>>(PT, ut);
        int gi = (num_movable + 255) / 256;
        instance_area<<<gi, 256, 0, stream>>>(pos, nsx, nsy, ut, out,
                                              num_movable, num_nodes);
        return;
    }

    // -------- fallback: round-1 style (768KB workspace) --------
    {
        float* G2   = (float*)d_ws;
        float* util = G2 + NB * NB * 2;    // utilT [x][y]
        fb_zero<<<256, 256, 0, stream>>>(G2, NB * NB * 2);
        int gn = (num_nets + 255) / 256;
        fb_scatter<<<gn, 256, 0, stream>>>(pin_pos, net_weights, netpin_start,
                                           flat_netpin, G2, num_nets, num_pins);
        fb_rowscan<<<NB, 256, 0, stream>>>((float2*)G2);
        fb_colscan<<<NB, 256, 0, stream>>>((const float2*)G2, util);
        int gi = (num_movable + 255) / 256;
        instance_area<<<gi, 256, 0, stream>>>(pos, nsx, nsy, util, out,
                                              num_movable, num_nodes);
    }
}

// Round 11
// 50.967 us; speedup vs baseline: 6.2094x; 1.1050x over previous
//
#include <hip/hip_runtime.h>

// InstanceRouteOptimizationArea — RUDY map via impulse/cumsum trick.
// Round 11: parallelism-max accum. R10 PMC: accum = 38.7us @ FETCH 1.6MB,
// VALU 15%, occ 13% -> not traffic, not ALU: starved of in-flight work
// (1 blk/CU, 24 branchy iters/thread). Fix: NW=8/NWIN=32/NCHUNK=32 ->
// grid 1024 = 4 blk/CU, 16 waves/CU, ~6 iters/thread; 1-bit wmask filter
// on a 4B load (yb/rd only on hit); chunk in low 5 bits (32%8==0) keeps a
// chunk's 100KB record slice on one XCD L2. Tail = R10's coalesced PT path.

#define NB 256
#define NW 8           // rows per window
#define NWIN 32        // NB/NW
#define NCHUNK 32      // grid K2 = NWIN*NCHUNK = 1024
#define K2_THREADS 512

__device__ __forceinline__ long long load_idx(const void* p, long long i, int is64) {
    if (is64) return ((const long long*)p)[i];
    return (long long)((const int*)p)[i];
}

// ---------------- K1: per-net bbox + wmask/yb/rd ----------------
__global__ void bbox_kernel(const float* __restrict__ pin_pos,
                            const float* __restrict__ net_weights,
                            const void* __restrict__ netpin_start,
                            const void* __restrict__ flat_netpin,
                            unsigned* __restrict__ wmask,
                            float2* __restrict__ yb,
                            float4* __restrict__ rd,
                            int num_nets, int num_pins) {
    int gid = blockIdx.x * blockDim.x + threadIdx.x;
    int n = gid >> 2, k = gid & 3;
    if (n >= num_nets) return;
    const int is64 = (((const int*)netpin_start)[1] == 0);
    long long s = load_idx(netpin_start, n, is64);
    long long e = load_idx(netpin_start, n + 1, is64);
    float xmn = 3e38f, xmx = -3e38f, ymn = 3e38f, ymx = -3e38f;
    if (e - s == 4) {
        long long pin = load_idx(flat_netpin, s + k, is64);
        float px = pin_pos[pin], py = pin_pos[pin + num_pins];
        xmn = px; xmx = px; ymn = py; ymx = py;
    } else if (k == 0) {
        for (long long p = s; p < e; ++p) {
            long long pin = load_idx(flat_netpin, p, is64);
            float px = pin_pos[pin], py = pin_pos[pin + num_pins];
            xmn = fminf(xmn, px); xmx = fmaxf(xmx, px);
            ymn = fminf(ymn, py); ymx = fmaxf(ymx, py);
        }
    }
    #pragma unroll
    for (int m = 1; m <= 2; m <<= 1) {
        xmn = fminf(xmn, __shfl_xor(xmn, m));
        xmx = fmaxf(xmx, __shfl_xor(xmx, m));
        ymn = fminf(ymn, __shfl_xor(ymn, m));
        ymx = fmaxf(ymx, __shfl_xor(ymx, m));
    }
    if (k) return;
    if (e <= s) { wmask[n] = 0u; return; }
    float wx = xmx - xmn, wy = ymx - ymn;
    float area = fmaxf(wx * wy, 1e-6f);
    float w = net_weights[n];
    const float INVB = 1.0f / 3.90625f;
    int j0 = (int)floorf(ymn * INVB);
    int j1 = (int)floorf(ymx * INVB);
    unsigned m = 0u;
    if ((unsigned)j0 < 256u)       m |= 1u << (j0 >> 3);
    if ((unsigned)(j0 + 1) < 256u) m |= 1u << ((j0 + 1) >> 3);
    if ((unsigned)j1 < 256u)       m |= 1u << (j1 >> 3);
    if ((unsigned)(j1 + 1) < 256u) m |= 1u << ((j1 + 1) >> 3);
    wmask[n] = m;
    yb[n] = make_float2(ymn, ymx);
    rd[n] = make_float4(xmn, xmx, w * wx / area, w * wy / area);
}

// ------- K2: bit-filter + LDS splat + x-cumsum + transposed PT store -------
__global__ __launch_bounds__(K2_THREADS) void accum5(
        const unsigned* __restrict__ wmask,
        const float2* __restrict__ yb,
        const float4* __restrict__ rd,
        float* __restrict__ PT,          // [NCHUNK][2][NB(x)][NB(y)]
        int num_nets) {
    __shared__ float acc[2 * NW * NB];   // 16 KiB: [plane][row][x]
    const int win   = blockIdx.x >> 5;   // 0..31
    const int chunk = blockIdx.x & 31;   // 0..31 (stride-32 blocks share XCD)
    const int r0    = win * NW;
    const int tid   = threadIdx.x;
    const float BSX  = 3.90625f;
    const float INVB = 1.0f / 3.90625f;

    for (int i = tid; i < 2 * NW * NB; i += K2_THREADS) acc[i] = 0.f;
    __syncthreads();

    const int c0 = (int)((long long)num_nets * chunk / NCHUNK);
    const int c1 = (int)((long long)num_nets * (chunk + 1) / NCHUNK);
    for (int n = c0 + tid; n < c1; n += K2_THREADS) {
        if (!((wmask[n] >> win) & 1u)) continue;
        float2 y = yb[n];
        float4 r = rd[n];
        float ty0 = y.x * INVB, fj0 = floorf(ty0); int j0 = (int)fj0; float f0 = ty0 - fj0;
        float ty1 = y.y * INVB, fj1 = floorf(ty1); int j1 = (int)fj1; float f1 = ty1 - fj1;
        float tx0 = r.x * INVB, g0 = floorf(tx0); int i0 = (int)g0; float h0 = tx0 - g0;
        float tx1 = r.y * INVB, g1 = floorf(tx1); int i1 = (int)g1; float h1 = tx1 - g1;
        int   xx[4] = { i0, i0 + 1, i1, i1 + 1 };
        float ax[4] = { BSX * (1.f - h0), BSX * h0, -BSX * (1.f - h1), -BSX * h1 };
        int   rr[4] = { j0, j0 + 1, j1, j1 + 1 };
        float rw[4] = { BSX * (1.f - f0), BSX * f0, -BSX * (1.f - f1), -BSX * f1 };
        #pragma unroll
        for (int q = 0; q < 4; ++q) {
            int ro = rr[q] - r0;
            if ((unsigned)ro >= NW) continue;
            float wh = rw[q] * r.z;
            float wv = rw[q] * r.w;
            float* bh = acc + ro * NB;
            float* bv = acc + NW * NB + ro * NB;
            #pragma unroll
            for (int p = 0; p < 4; ++p) {
                int x = xx[p];
                if (x >= NB) continue;
                atomicAdd(bh + x, ax[p] * wh);
                atomicAdd(bv + x, ax[p] * wv);
            }
        }
    }
    __syncthreads();

    // x-cumsum: 16 rows (2 planes x 8), one wave per 2 rows.
    const int wave = tid >> 6, lane = tid & 63;
    for (int row = wave; row < 2 * NW; row += (K2_THREADS / 64)) {
        float* base = acc + row * NB;
        float carry = 0.f;
        #pragma unroll
        for (int seg = 0; seg < NB / 64; ++seg) {
            float v = base[seg * 64 + lane];
            #pragma unroll
            for (int off = 1; off < 64; off <<= 1) {
                float u = __shfl_up(v, off);
                if (lane >= off) v += u;
            }
            v += carry;
            base[seg * 64 + lane] = v;
            carry = __shfl(v, 63);
        }
    }
    __syncthreads();

    // Transposed store: PT[chunk][plane][x][r0..r0+8) as 2x float4 per x.
    for (int i = tid; i < 2 * NB * 2; i += K2_THREADS) {
        int p    = i >> 9;          // plane
        int rem  = i & 511;
        int x    = rem >> 1;
        int half = rem & 1;
        int base = p * NW * NB;
        float4 v;
        v.x = acc[base + (half * 4 + 0) * NB + x];
        v.y = acc[base + (half * 4 + 1) * NB + x];
        v.z = acc[base + (half * 4 + 2) * NB + x];
        v.w = acc[base + (half * 4 + 3) * NB + x];
        float* dst = PT + ((((long long)chunk * 2 + p) * NB + x) * NB) + r0 + half * 4;
        *(float4*)dst = v;
    }
}

// ---------------- K3: chunk-sum + y-cumsum + util (all coalesced) --------
__global__ __launch_bounds__(512) void yscan_util(
        const float* __restrict__ PT, float* __restrict__ utilT) {
    __shared__ float buf[2 * NB];
    const int x = blockIdx.x;
    const int plane = threadIdx.x >> 8;
    const int y = threadIdx.x & (NB - 1);
    float s = 0.f;
    #pragma unroll 8
    for (int c = 0; c < NCHUNK; ++c)
        s += PT[(((long long)c * 2 + plane) * NB + x) * NB + y];
    float* b = buf + plane * NB;
    b[y] = s;
    #pragma unroll
    for (int off = 1; off < NB; off <<= 1) {
        __syncthreads();
        float a = (y >= off) ? b[y - off] : 0.0f;
        __syncthreads();
        b[y] += a;
    }
    __syncthreads();
    if (plane == 0) {
        const float INV_CH = 1.0f / (3.90625f * 3.90625f * 1.5625f);
        const float INV_CV = 1.0f / (3.90625f * 3.90625f * 1.45f);
        float u = fmaxf(buf[y] * INV_CH, buf[NB + y] * INV_CV);
        u = fminf(fmaxf(u, 0.5f), 2.0f);
        utilT[x * NB + y] = u;
    }
}

// ---------------- K4: per-instance area (util transposed [x][y]) --------
__global__ void instance_area(const float* __restrict__ pos,
                              const float* __restrict__ nsx,
                              const float* __restrict__ nsy,
                              const float* __restrict__ utilT,
                              float* __restrict__ out,
                              int num_movable, int num_nodes) {
    int i = blockIdx.x * blockDim.x + threadIdx.x;
    if (i >= num_movable) return;
    const float BSX = 3.90625f;
    const float INVB = 1.0f / 3.90625f;
    float x0f = pos[i];
    float y0f = pos[num_nodes + i];
    float x1f = x0f + nsx[i];
    float y1f = y0f + nsy[i];
    int kx0 = max(0, min(NB - 1, (int)floorf(x0f * INVB)));
    int kx1 = max(0, min(NB - 1, (int)floorf(x1f * INVB)));
    int ky0 = max(0, min(NB - 1, (int)floorf(y0f * INVB)));
    int ky1 = max(0, min(NB - 1, (int)floorf(y1f * INVB)));
    float acc = 0.0f;
    for (int kx = kx0; kx <= kx1; ++kx) {
        float bx = kx * BSX;
        float ovx = fmaxf(fminf(x1f, bx + BSX) - fmaxf(x0f, bx), 0.0f);
        const float* ucol = utilT + kx * NB;
        float accy = 0.0f;
        for (int ky = ky0; ky <= ky1; ++ky) {
            float by = ky * BSX;
            float ovy = fmaxf(fminf(y1f, by + BSX) - fmaxf(y0f, by), 0.0f);
            accy += ovy * ucol[ky];
        }
        acc += accy * ovx;
    }
    out[i] = acc;
}

// ---------------- fallback (tiny workspace): round-1 style ----------------
__global__ void fb_zero(float* g, int n) {
    int i = blockIdx.x * blockDim.x + threadIdx.x;
    int stride = gridDim.x * blockDim.x;
    for (; i < n; i += stride) g[i] = 0.0f;
}

__global__ void fb_scatter(const float* __restrict__ pin_pos,
                           const float* __restrict__ net_weights,
                           const void* __restrict__ netpin_start,
                           const void* __restrict__ flat_netpin,
                           float* __restrict__ G2,
                           int num_nets, int num_pins) {
    int n = blockIdx.x * blockDim.x + threadIdx.x;
    if (n >= num_nets) return;
    const int is64 = (((const int*)netpin_start)[1] == 0);
    long long s = load_idx(netpin_start, n, is64);
    long long e = load_idx(netpin_start, n + 1, is64);
    if (e <= s) return;
    float xmn = 3e38f, xmx = -3e38f, ymn = 3e38f, ymx = -3e38f;
    for (long long p = s; p < e; ++p) {
        long long pin = load_idx(flat_netpin, p, is64);
        float px = pin_pos[pin], py = pin_pos[pin + num_pins];
        xmn = fminf(xmn, px); xmx = fmaxf(xmx, px);
        ymn = fminf(ymn, py); ymx = fmaxf(ymx, py);
    }
    float wx = xmx - xmn, wy = ymx - ymn;
    float area = fmaxf(wx * wy, 1e-6f);
    float w = net_weights[n];
    float dh = w * wx / area, dv = w * wy / area;
    const float BSX = 3.90625f, INVB = 1.0f / 3.90625f;
    int jx[4]; float ax[4]; int jy[4]; float ay[4];
    float t, fj, f; int j;
    t = xmn * INVB; fj = floorf(t); j = (int)fj; f = t - fj;
    jx[0] = j; ax[0] = BSX * (1.f - f); jx[1] = j + 1; ax[1] = BSX * f;
    t = xmx * INVB; fj = floorf(t); j = (int)fj; f = t - fj;
    jx[2] = j; ax[2] = -BSX * (1.f - f); jx[3] = j + 1; ax[3] = -BSX * f;
    t = ymn * INVB; fj = floorf(t); j = (int)fj; f = t - fj;
    jy[0] = j; ay[0] = BSX * (1.f - f); jy[1] = j + 1; ay[1] = BSX * f;
    t = ymx * INVB; fj = floorf(t); j = (int)fj; f = t - fj;
    jy[2] = j; ay[2] = -BSX * (1.f - f); jy[3] = j + 1; ay[3] = -BSX * f;
    #pragma unroll
    for (int b = 0; b < 4; ++b) {
        int y = jy[b];
        if (y < 0 || y >= NB) continue;
        #pragma unroll
        for (int a2 = 0; a2 < 4; ++a2) {
            int x = jx[a2];
            if (x < 0 || x >= NB) continue;
            float g = ax[a2] * ay[b];
            atomicAdd(&G2[(y * NB + x) * 2],     dh * g);
            atomicAdd(&G2[(y * NB + x) * 2 + 1], dv * g);
        }
    }
}

__global__ void fb_rowscan(float2* G2) {
    int y = blockIdx.x, t = threadIdx.x;
    __shared__ float sh[NB]; __shared__ float sv[NB];
    float2 v = G2[y * NB + t];
    sh[t] = v.x; sv[t] = v.y;
    #pragma unroll
    for (int off = 1; off < NB; off <<= 1) {
        __syncthreads();
        float a = (t >= off) ? sh[t - off] : 0.0f;
        float b = (t >= off) ? sv[t - off] : 0.0f;
        __syncthreads();
        sh[t] += a; sv[t] += b;
    }
    __syncthreads();
    G2[y * NB + t] = make_float2(sh[t], sv[t]);
}

__global__ void fb_colscan(const float2* __restrict__ G2, float* __restrict__ utilT) {
    int x = blockIdx.x, t = threadIdx.x;
    const float INV_CH = 1.0f / (3.90625f * 3.90625f * 1.5625f);
    const float INV_CV = 1.0f / (3.90625f * 3.90625f * 1.45f);
    __shared__ float sh[NB]; __shared__ float sv[NB];
    float2 g = G2[t * NB + x];
    sh[t] = g.x; sv[t] = g.y;
    #pragma unroll
    for (int off = 1; off < NB; off <<= 1) {
        __syncthreads();
        float a = (t >= off) ? sh[t - off] : 0.0f;
        float b = (t >= off) ? sv[t - off] : 0.0f;
        __syncthreads();
        sh[t] += a; sv[t] += b;
    }
    __syncthreads();
    float u = fmaxf(sh[t] * INV_CH, sv[t] * INV_CV);
    utilT[x * NB + t] = fminf(fmaxf(u, 0.5f), 2.0f);
}

extern "C" void kernel_launch(void* const* d_in, const int* in_sizes, int n_in,
                              void* d_out, int out_size, void* d_ws, size_t ws_size,
                              hipStream_t stream) {
    const float* pos          = (const float*)d_in[0];
    const float* pin_pos      = (const float*)d_in[1];
    const float* nsx          = (const float*)d_in[2];
    const float* nsy          = (const float*)d_in[3];
    const float* net_weights  = (const float*)d_in[4];
    const void*  netpin_start = d_in[5];
    const void*  flat_netpin  = d_in[6];
    float* out = (float*)d_out;

    int num_pins    = in_sizes[1] / 2;
    int num_nodes   = in_sizes[2];
    int num_nets    = in_sizes[4];
    int num_movable = out_size;

    // ws (floats): wmask[n] | yb[2n] | rd[4n] | PT[32*2*NB*NB] | utilT[NB*NB]
    auto align4 = [](size_t v) { return (v + 3) & ~(size_t)3; };
    size_t mk_off = 0;
    size_t yb_off = align4(mk_off + (size_t)num_nets);
    size_t rd_off = align4(yb_off + 2LL * num_nets);
    size_t PT_off = align4(rd_off + 4LL * num_nets);
    size_t PT_f   = (size_t)NCHUNK * 2 * NB * NB;
    size_t ut_off = PT_off + PT_f;
    size_t need   = (ut_off + (size_t)NB * NB) * sizeof(float);

    if (ws_size >= need) {
        float* base = (float*)d_ws;
        unsigned* wmask = (unsigned*)(base + mk_off);
        float2*   yb    = (float2*)(base + yb_off);
        float4*   rd    = (float4*)(base + rd_off);
        float*    PT    = base + PT_off;
        float*    ut    = base + ut_off;

        int g1 = (4 * num_nets + 255) / 256;
        bbox_kernel<<<g1, 256, 0, stream>>>(pin_pos, net_weights, netpin_start,
                                            flat_netpin, wmask, yb, rd,
                                            num_nets, num_pins);
        accum5<<<NWIN * NCHUNK, K2_THREADS, 0, stream>>>(wmask, yb, rd, PT, num_nets);
        yscan_util<<<NB, 512, 0, stream>>>(PT, ut);
        int gi = (num_movable + 255) / 256;
        instance_area<<<gi, 256, 0, stream>>>(pos, nsx, nsy, ut, out,
                                              num_movable, num_nodes);
        return;
    }

    // -------- fallback: round-1 style (768KB workspace) --------
    {
        float* G2   = (float*)d_ws;
        float* util = G2 + NB * NB * 2;    // utilT [x][y]
        fb_zero<<<256, 256, 0, stream>>>(G2, NB * NB * 2);
        int gn = (num_nets + 255) / 256;
        fb_scatter<<<gn, 256, 0, stream>>>(pin_pos, net_weights, netpin_start,
                                           flat_netpin, G2, num_nets, num_pins);
        fb_rowscan<<<NB, 256, 0, stream>>>((float2*)G2);
        fb_colscan<<<NB, 256, 0, stream>>>((const float2*)G2, util);
        int gi = (num_movable + 255) / 256;
        instance_area<<<gi, 256, 0, stream>>>(pos, nsx, nsy, util, out,
                                              num_movable, num_nodes);
    }
}